// Round 1
// baseline (532.749 us; speedup 1.0000x reference)
//
#include <hip/hip_runtime.h>

// SOBA-Monarch, B*H=64 heads, S=4096, D=64, nb=bs=64, pad=0, 3 steps.
// f32 correctness-first implementation; batched 64x64x64 matmuls.
// ws layout (needs ~131 MiB):
//   G   [h][k][j][v]  64 MiB   (also reused as z staging by the last kernel)
//   Hm  [h][j][k][v]  64 MiB
//   M   [h][j][v]      1 MiB   (step-0 G, k-independent)
//   al  [h][k][j]      1 MiB
//   tau [h][k][j]      1 MiB
// Y [h][j][k][v] staged in d_out; final z copied G-buffer -> d_out.

namespace {

constexpr int PAD   = 68;        // LDS row stride (floats): 16B-aligned, bank-spread
constexpr int HEADS = 64;        // B*H
constexpr int SEQ   = 4096;
constexpr size_t HEADQ = (size_t)SEQ * 64;        // floats per head in Q/K/V (262144)
constexpr size_t MATF  = (size_t)HEADS * 64 * 64 * 64; // floats in G/Hm/Y (16.7M)

__device__ __forceinline__ float rmax16(float m) {
    m = fmaxf(m, __shfl_xor(m, 1));
    m = fmaxf(m, __shfl_xor(m, 2));
    m = fmaxf(m, __shfl_xor(m, 4));
    m = fmaxf(m, __shfl_xor(m, 8));
    return m;
}
__device__ __forceinline__ float rsum16(float s) {
    s += __shfl_xor(s, 1);
    s += __shfl_xor(s, 2);
    s += __shfl_xor(s, 4);
    s += __shfl_xor(s, 8);
    return s;
}

#define FMA16(ACC, A, B) do { \
    ACC[0][0] = fmaf(A.x, B.x, ACC[0][0]); ACC[0][1] = fmaf(A.x, B.y, ACC[0][1]); \
    ACC[0][2] = fmaf(A.x, B.z, ACC[0][2]); ACC[0][3] = fmaf(A.x, B.w, ACC[0][3]); \
    ACC[1][0] = fmaf(A.y, B.x, ACC[1][0]); ACC[1][1] = fmaf(A.y, B.y, ACC[1][1]); \
    ACC[1][2] = fmaf(A.y, B.z, ACC[1][2]); ACC[1][3] = fmaf(A.y, B.w, ACC[1][3]); \
    ACC[2][0] = fmaf(A.z, B.x, ACC[2][0]); ACC[2][1] = fmaf(A.z, B.y, ACC[2][1]); \
    ACC[2][2] = fmaf(A.z, B.z, ACC[2][2]); ACC[2][3] = fmaf(A.z, B.w, ACC[2][3]); \
    ACC[3][0] = fmaf(A.w, B.x, ACC[3][0]); ACC[3][1] = fmaf(A.w, B.y, ACC[3][1]); \
    ACC[3][2] = fmaf(A.w, B.z, ACC[3][2]); ACC[3][3] = fmaf(A.w, B.w, ACC[3][3]); \
} while (0)

// M[h][j][v] = (1/64) * sum_l Q[h][l*64+j][v] / 8
__global__ void kmean_kernel(const float* __restrict__ Q, float* __restrict__ M) {
    const int wg = blockIdx.x;            // h*64 + j
    const int h  = wg >> 6, j = wg & 63;
    const int v  = threadIdx.x;           // 64 threads
    const float* base = Q + (size_t)h * HEADQ + (size_t)j * 64 + v;
    float acc = 0.f;
    #pragma unroll
    for (int l = 0; l < 64; ++l) acc += base[(size_t)l * 4096];
    M[(size_t)wg * 64 + v] = acc * (1.0f / 512.0f);
}

// One WG per (h,k). beta_k = G_k @ K_k^T ; right = softmax_i(beta/tau);
// alpha_k[j] = sum_i r log r ; Hm_k = right @ K_k ; (LAST: Y_k = right @ V_k)
template<int FIRST, int LAST>
__global__ __launch_bounds__(256) void bc_kernel(
    const float* __restrict__ Gsrc,   // FIRST ? M : G
    const float* __restrict__ Kmat,
    const float* __restrict__ Vmat,   // LAST only
    const float* __restrict__ tauIn,  // !FIRST only
    float* __restrict__ Hm,
    float* __restrict__ alphaOut,
    float* __restrict__ Yout)         // LAST only
{
    __shared__ float sGt[64 * PAD];   // [v][j] G^T ; later right^T [i][j]
    __shared__ float sKt[64 * PAD];   // [v][i] K^T ; later (LAST) V row-major [i][v]
    __shared__ float sK [64 * PAD];   // [i][v]
    __shared__ float sTau[64];

    const int wg = blockIdx.x;
    const int h = wg >> 6, k = wg & 63;
    const int tid = threadIdx.x;

    { // ---- stage G (transposed), K (both layouts) ----
        const int r  = tid >> 2;
        const int v0 = (tid & 3) << 4;
        const float* gk = Gsrc + (FIRST ? (size_t)h * 4096 : (size_t)wg * 4096) + r * 64 + v0;
        const float* kk = Kmat + (size_t)h * HEADQ + (size_t)k * 4096 + r * 64 + v0;
        #pragma unroll
        for (int q4 = 0; q4 < 4; ++q4) {
            float4 gv = *(const float4*)(gk + 4 * q4);
            float4 kv = *(const float4*)(kk + 4 * q4);
            const int vb = v0 + 4 * q4;
            sGt[(vb + 0) * PAD + r] = gv.x; sGt[(vb + 1) * PAD + r] = gv.y;
            sGt[(vb + 2) * PAD + r] = gv.z; sGt[(vb + 3) * PAD + r] = gv.w;
            sKt[(vb + 0) * PAD + r] = kv.x; sKt[(vb + 1) * PAD + r] = kv.y;
            sKt[(vb + 2) * PAD + r] = kv.z; sKt[(vb + 3) * PAD + r] = kv.w;
            *(float4*)(&sK[r * PAD + vb]) = kv;
        }
        if (!FIRST && tid < 64) sTau[tid] = tauIn[(size_t)wg * 64 + tid];
    }
    __syncthreads();

    const int ty = tid >> 4, tx = tid & 15;

    // ---- MM1: beta[j,i] = sum_v G[j,v] K[i,v] ----
    float acc[4][4] = {};
    #pragma unroll 8
    for (int v = 0; v < 64; ++v) {
        float4 a = *(const float4*)(&sGt[v * PAD + 4 * ty]);
        float4 b = *(const float4*)(&sKt[v * PAD + 4 * tx]);
        FMA16(acc, a, b);
    }

    // ---- softmax over i (across tx), /tau, alpha ----
    float rv[4][4];
    #pragma unroll
    for (int r = 0; r < 4; ++r) {
        const float tv = FIRST ? 1.0f : sTau[4 * ty + r];
        const bool tz = !(tv > 1e-8f);
        const float tvi = tz ? 1.0f : (1.0f / tv);
        float lg[4];
        #pragma unroll
        for (int c = 0; c < 4; ++c) lg[c] = acc[r][c] * tvi;
        float m = fmaxf(fmaxf(lg[0], lg[1]), fmaxf(lg[2], lg[3]));
        m = rmax16(m);
        float e[4], s = 0.f;
        #pragma unroll
        for (int c = 0; c < 4; ++c) { e[c] = __expf(lg[c] - m); s += e[c]; }
        s = rsum16(s);
        const float inv = 1.0f / s;
        float ap = 0.f;
        #pragma unroll
        for (int c = 0; c < 4; ++c) {
            float rr = tz ? (1.0f / 64.0f) : e[c] * inv;
            rv[r][c] = rr;
            ap += (rr > 0.f) ? rr * __logf(rr) : 0.f;
        }
        ap = rsum16(ap);
        if (tx == 0) alphaOut[(size_t)wg * 64 + 4 * ty + r] = ap;
    }
    __syncthreads();                   // everyone done reading sGt / sKt

    // right^T into sGt space: sRt[i][j]
    #pragma unroll
    for (int r = 0; r < 4; ++r)
        #pragma unroll
        for (int c = 0; c < 4; ++c)
            sGt[(4 * tx + c) * PAD + 4 * ty + r] = rv[r][c];
    if (LAST) {                        // V row-major into sKt space
        const int r  = tid >> 2;
        const int v0 = (tid & 3) << 4;
        const float* vv = Vmat + (size_t)h * HEADQ + (size_t)k * 4096 + r * 64 + v0;
        #pragma unroll
        for (int q4 = 0; q4 < 4; ++q4)
            *(float4*)(&sKt[r * PAD + v0 + 4 * q4]) = *(const float4*)(vv + 4 * q4);
    }
    __syncthreads();

    // ---- MM2: Hm[j,v] = sum_i right[j,i] K[i,v] (+ LAST: Y = right @ V) ----
    float acc2[4][4] = {};
    float acc3[4][4] = {};
    #pragma unroll 8
    for (int i = 0; i < 64; ++i) {
        float4 a = *(const float4*)(&sGt[i * PAD + 4 * ty]);
        float4 b = *(const float4*)(&sK [i * PAD + 4 * tx]);
        FMA16(acc2, a, b);
        if (LAST) {
            float4 bv = *(const float4*)(&sKt[i * PAD + 4 * tx]);
            FMA16(acc3, a, bv);
        }
    }
    #pragma unroll
    for (int r = 0; r < 4; ++r) {
        const int j = 4 * ty + r;
        const size_t off = (size_t)h * MATF / HEADS + (size_t)j * 4096 + (size_t)k * 64 + 4 * tx;
        *(float4*)(Hm + off) = make_float4(acc2[r][0], acc2[r][1], acc2[r][2], acc2[r][3]);
        if (LAST)
            *(float4*)(Yout + off) = make_float4(acc3[r][0], acc3[r][1], acc3[r][2], acc3[r][3]);
    }
}

// One WG per (h,j). beta2[l,k] = sum_v q[l,v] Hm[k,v]; left = softmax_k(beta2 - alpha);
// !LAST: tau[k] = colsum(left), G[k,v] = sum_l left[l,k] q[l,v]
//  LAST: Z[l,v] = sum_k left[l,k] Y[k,v]  -> z staging buffer
template<int LAST>
__global__ __launch_bounds__(256) void da_kernel(
    const float* __restrict__ Q,
    const float* __restrict__ Hm,
    const float* __restrict__ alphaIn,
    const float* __restrict__ Yin,    // LAST only
    float* __restrict__ Gout,         // !LAST
    float* __restrict__ tauOut,       // !LAST
    float* __restrict__ Zout)         // LAST
{
    __shared__ float sQt[64 * PAD];   // [v][l] scaled q^T
    __shared__ float sB [64 * PAD];   // [v][k] Hm^T ; later left ([l][k] or [k][l])
    __shared__ float sC [64 * PAD];   // !LAST: scaled q row-major [l][v] ; LAST: Y [k][v]
    __shared__ float sA [64];

    const int wg = blockIdx.x;
    const int h = wg >> 6, j = wg & 63;
    const int tid = threadIdx.x;

    { // ---- stage q (x0.125), Hm^T, (LAST) Y ----
        const int r  = tid >> 2;
        const int v0 = (tid & 3) << 4;
        const float* qrow = Q  + (size_t)h * HEADQ + (size_t)r * 4096 + (size_t)j * 64 + v0;
        const float* hrow = Hm + (size_t)wg * 4096 + r * 64 + v0;
        #pragma unroll
        for (int q4 = 0; q4 < 4; ++q4) {
            float4 qv = *(const float4*)(qrow + 4 * q4);
            qv.x *= 0.125f; qv.y *= 0.125f; qv.z *= 0.125f; qv.w *= 0.125f;
            float4 hv = *(const float4*)(hrow + 4 * q4);
            const int vb = v0 + 4 * q4;
            sQt[(vb + 0) * PAD + r] = qv.x; sQt[(vb + 1) * PAD + r] = qv.y;
            sQt[(vb + 2) * PAD + r] = qv.z; sQt[(vb + 3) * PAD + r] = qv.w;
            sB [(vb + 0) * PAD + r] = hv.x; sB [(vb + 1) * PAD + r] = hv.y;
            sB [(vb + 2) * PAD + r] = hv.z; sB [(vb + 3) * PAD + r] = hv.w;
            if (!LAST) *(float4*)(&sC[r * PAD + vb]) = qv;
        }
        if (LAST) {
            const float* yrow = Yin + (size_t)wg * 4096 + r * 64 + v0;
            #pragma unroll
            for (int q4 = 0; q4 < 4; ++q4)
                *(float4*)(&sC[r * PAD + v0 + 4 * q4]) = *(const float4*)(yrow + 4 * q4);
        }
        if (tid < 64) sA[tid] = alphaIn[((size_t)h * 64 + tid) * 64 + j];
    }
    __syncthreads();

    const int ty = tid >> 4, tx = tid & 15;

    // ---- MM1: beta2[l,k] ----
    float acc[4][4] = {};
    #pragma unroll 8
    for (int v = 0; v < 64; ++v) {
        float4 a = *(const float4*)(&sQt[v * PAD + 4 * ty]);
        float4 b = *(const float4*)(&sB [v * PAD + 4 * tx]);
        FMA16(acc, a, b);
    }

    // ---- left = softmax over k (across tx) of (beta2 - alpha[k]) ----
    float lv[4][4];
    #pragma unroll
    for (int r = 0; r < 4; ++r) {
        float lg[4];
        #pragma unroll
        for (int c = 0; c < 4; ++c) lg[c] = acc[r][c] - sA[4 * tx + c];
        float m = fmaxf(fmaxf(lg[0], lg[1]), fmaxf(lg[2], lg[3]));
        m = rmax16(m);
        float e[4], s = 0.f;
        #pragma unroll
        for (int c = 0; c < 4; ++c) { e[c] = __expf(lg[c] - m); s += e[c]; }
        s = rsum16(s);
        const float inv = 1.0f / s;
        #pragma unroll
        for (int c = 0; c < 4; ++c) lv[r][c] = e[c] * inv;
    }
    __syncthreads();                   // done reading sB (Hm^T)

    if (!LAST) {                       // left row-major [l][k]
        #pragma unroll
        for (int r = 0; r < 4; ++r)
            *(float4*)(&sB[(4 * ty + r) * PAD + 4 * tx]) =
                make_float4(lv[r][0], lv[r][1], lv[r][2], lv[r][3]);
    } else {                           // left^T [k][l]
        #pragma unroll
        for (int r = 0; r < 4; ++r)
            #pragma unroll
            for (int c = 0; c < 4; ++c)
                sB[(4 * tx + c) * PAD + 4 * ty + r] = lv[r][c];
    }
    __syncthreads();

    if (!LAST) {
        if (tid < 64) {                // tau[k] = sum_l left[l][k]
            float s = 0.f;
            #pragma unroll
            for (int l = 0; l < 64; ++l) s += sB[l * PAD + tid];
            tauOut[((size_t)h * 64 + tid) * 64 + j] = s;
        }
        // G[k,v] = sum_l left[l,k] q[l,v]
        float acc2[4][4] = {};
        #pragma unroll 8
        for (int l = 0; l < 64; ++l) {
            float4 a = *(const float4*)(&sB[l * PAD + 4 * ty]);  // left[l][4ty..]
            float4 b = *(const float4*)(&sC[l * PAD + 4 * tx]);  // q[l][4tx..]
            FMA16(acc2, a, b);
        }
        #pragma unroll
        for (int r = 0; r < 4; ++r) {
            const int kq = 4 * ty + r;
            *(float4*)(Gout + ((size_t)h * 64 + kq) * 4096 + (size_t)j * 64 + 4 * tx) =
                make_float4(acc2[r][0], acc2[r][1], acc2[r][2], acc2[r][3]);
        }
    } else {
        // Z[l,v] = sum_k left[l,k] Y[k,v]
        float acc2[4][4] = {};
        #pragma unroll 8
        for (int kk = 0; kk < 64; ++kk) {
            float4 a = *(const float4*)(&sB[kk * PAD + 4 * ty]); // left^T[k][4ty..]
            float4 b = *(const float4*)(&sC[kk * PAD + 4 * tx]); // Y[k][4tx..]
            FMA16(acc2, a, b);
        }
        #pragma unroll
        for (int r = 0; r < 4; ++r) {
            const int l = 4 * ty + r;
            *(float4*)(Zout + (size_t)h * HEADQ + (size_t)l * 4096 + (size_t)j * 64 + 4 * tx) =
                make_float4(acc2[r][0], acc2[r][1], acc2[r][2], acc2[r][3]);
        }
    }
}

} // namespace

extern "C" void kernel_launch(void* const* d_in, const int* in_sizes, int n_in,
                              void* d_out, int out_size, void* d_ws, size_t ws_size,
                              hipStream_t stream) {
    const float* Q = (const float*)d_in[0];
    const float* K = (const float*)d_in[1];
    const float* V = (const float*)d_in[2];
    float* out = (float*)d_out;

    char* ws = (char*)d_ws;
    const size_t MB = 1024 * 1024;
    float* G   = (float*)(ws);                  // 64 MiB (later: z staging)
    float* Hm  = (float*)(ws + 64 * MB);        // 64 MiB
    float* M   = (float*)(ws + 128 * MB);       //  1 MiB
    float* al  = (float*)(ws + 129 * MB);       //  1 MiB
    float* tau = (float*)(ws + 130 * MB);       //  1 MiB
    float* Y   = out;                            // Y staged in d_out

    dim3 blk(256), grid(HEADS * 64);

    kmean_kernel<<<dim3(HEADS * 64), dim3(64), 0, stream>>>(Q, M);
    bc_kernel<1, 0><<<grid, blk, 0, stream>>>(M, K, nullptr, nullptr, Hm, al, nullptr);
    da_kernel<0>   <<<grid, blk, 0, stream>>>(Q, Hm, al, nullptr, G, tau, nullptr);
    bc_kernel<0, 0><<<grid, blk, 0, stream>>>(G, K, nullptr, tau, Hm, al, nullptr);
    da_kernel<0>   <<<grid, blk, 0, stream>>>(Q, Hm, al, nullptr, G, tau, nullptr);
    bc_kernel<0, 1><<<grid, blk, 0, stream>>>(G, K, V, tau, Hm, al, Y);
    da_kernel<1>   <<<grid, blk, 0, stream>>>(Q, Hm, al, Y, nullptr, nullptr, G);
    hipMemcpyAsync(d_out, G, MATF * sizeof(float), hipMemcpyDeviceToDevice, stream);
}

// Round 2
// 385.840 us; speedup vs baseline: 1.3808x; 1.3808x over previous
//
#include <hip/hip_runtime.h>

// SOBA-Monarch, B*H=64 heads, S=4096, D=64, nb=bs=64, pad=0, 3 steps.
// Round 2: all 64x64x64 matmuls on MFMA (mfma_f32_16x16x32_bf16) with
// split-bf16 (hi+lo) operands for ~fp32 accuracy (3 MFMAs per product).
// LDS: bf16 [64][64] tiles, 16B-chunk XOR swizzle -> conflict-free b128 frag loads.
// ws layout: G 64MB | Hm 64MB | M 1MB | al 1MB | tau 1MB | (Y 64MB if ws allows)

namespace {

typedef __attribute__((ext_vector_type(8))) short short8v;
typedef __attribute__((ext_vector_type(4))) float f32x4;

constexpr int HEADS = 64;                       // B*H
constexpr size_t HEADQ = 262144;                // 4096*64 floats per head
constexpr size_t MATF  = (size_t)HEADS * 262144; // floats in G/Hm/Y/z

#define MFMA(ACC, A, B) ACC = __builtin_amdgcn_mfma_f32_16x16x32_bf16(A, B, ACC, 0, 0, 0)

__device__ __forceinline__ float rmax16(float m) {
    m = fmaxf(m, __shfl_xor(m, 1));
    m = fmaxf(m, __shfl_xor(m, 2));
    m = fmaxf(m, __shfl_xor(m, 4));
    m = fmaxf(m, __shfl_xor(m, 8));
    return m;
}
__device__ __forceinline__ float rsum16(float s) {
    s += __shfl_xor(s, 1);
    s += __shfl_xor(s, 2);
    s += __shfl_xor(s, 4);
    s += __shfl_xor(s, 8);
    return s;
}

__device__ __forceinline__ ushort bf_rne(float x) {
    uint u = __float_as_uint(x);
    return (ushort)((u + 0x7FFFu + ((u >> 16) & 1u)) >> 16);
}
__device__ __forceinline__ float bf2f(ushort h) { return __uint_as_float(((uint)h) << 16); }

// swizzled index helpers for bf16 [64][64] LDS tiles (8 chunks of 8 ushorts/row)
__device__ __forceinline__ int swz_idx(int row, int col) {
    return row * 64 + ((((col >> 3) ^ (row & 7)) << 3)) + (col & 7);
}
__device__ __forceinline__ short8v ldfrag(const ushort* s, int row, int chunk) {
    return *(const short8v*)(s + row * 64 + ((chunk ^ (row & 7)) << 3));
}

// stage a 64x64 f32 tile (thread: row r=tid>>2, cols c0..c0+15) into hi/lo bf16
// LDS arrays; ROW: row-major [r][c]; TR: transposed [c][r].
template<bool ROW, bool TR>
__device__ __forceinline__ void stage16(const float* __restrict__ gsrc, float scale,
                                        ushort* rh, ushort* rl, ushort* th, ushort* tl,
                                        int r, int c0) {
    float v[16];
    #pragma unroll
    for (int q = 0; q < 4; ++q) {
        float4 f = *(const float4*)(gsrc + 4 * q);
        v[4*q+0] = f.x * scale; v[4*q+1] = f.y * scale;
        v[4*q+2] = f.z * scale; v[4*q+3] = f.w * scale;
    }
    ushort vh[16], vl[16];
    #pragma unroll
    for (int e = 0; e < 16; ++e) {
        ushort hh = bf_rne(v[e]);
        vh[e] = hh;
        vl[e] = bf_rne(v[e] - bf2f(hh));
    }
    if (ROW) {
        #pragma unroll
        for (int q = 0; q < 2; ++q) {
            short8v ph, pl;
            #pragma unroll
            for (int e = 0; e < 8; ++e) { ph[e] = (short)vh[8*q+e]; pl[e] = (short)vl[8*q+e]; }
            const int chunk = (c0 >> 3) + q;
            const int off = r * 64 + ((chunk ^ (r & 7)) << 3);
            *(short8v*)(rh + off) = ph;
            *(short8v*)(rl + off) = pl;
        }
    }
    if (TR) {
        #pragma unroll
        for (int e = 0; e < 16; ++e) {
            const int jj = (e + r) & 15;             // phase-rotate to spread banks
            const int idx = swz_idx(c0 + jj, r);
            th[idx] = vh[jj]; tl[idx] = vl[jj];
        }
    }
}

// M[h][j][v] = (1/64) * sum_l Q[h][l*64+j][v] / 8
__global__ void kmean_kernel(const float* __restrict__ Q, float* __restrict__ M) {
    const int wg = blockIdx.x;            // h*64 + j
    const int h  = wg >> 6, j = wg & 63;
    const int v  = threadIdx.x;           // 64 threads
    const float* base = Q + (size_t)h * HEADQ + (size_t)j * 64 + v;
    float acc = 0.f;
    #pragma unroll
    for (int l = 0; l < 64; ++l) acc += base[(size_t)l * 4096];
    M[(size_t)wg * 64 + v] = acc * (1.0f / 512.0f);
}

// One WG (256T, 4 waves) per (h,k).
// MM1: beta[j,i] = sum_v G[j,v] K[i,v]; softmax_i(beta/tau); alpha[j]=sum r log r
// MM2: Hm[j,v] = sum_i right[j,i] K[i,v];  LAST: Y[j,v] = sum_i right[j,i] V[i,v]
template<int FIRST, int LAST>
__global__ __launch_bounds__(256) void bc_kernel(
    const float* __restrict__ Gsrc,   // FIRST ? M : G
    const float* __restrict__ Kmat,
    const float* __restrict__ Vmat,   // LAST only
    const float* __restrict__ tauIn,  // !FIRST only
    float* __restrict__ Hm,
    float* __restrict__ alphaOut,
    float* __restrict__ Yout)         // LAST only
{
    __shared__ __align__(16) ushort sGh[4096], sGl[4096];  // G rows -> right rows
    __shared__ __align__(16) ushort sKh[4096], sKl[4096];  // K rows -> V^T (LAST)
    __shared__ __align__(16) ushort sTh[4096], sTl[4096];  // K^T [v][i]
    __shared__ float sTau[64];

    const int wg = blockIdx.x, h = wg >> 6, k = wg & 63;
    const int tid = threadIdx.x;
    const int r = tid >> 2, c0 = (tid & 3) << 4;

    const float* gp = Gsrc + (FIRST ? (size_t)h * 4096 : (size_t)wg * 4096) + r * 64 + c0;
    stage16<true, false>(gp, 1.f, sGh, sGl, nullptr, nullptr, r, c0);
    const float* kp = Kmat + (size_t)h * HEADQ + (size_t)k * 4096 + r * 64 + c0;
    stage16<true, true>(kp, 1.f, sKh, sKl, sTh, sTl, r, c0);
    float vfl[16];
    if (LAST) {
        const float* vp = Vmat + (size_t)h * HEADQ + (size_t)k * 4096 + r * 64 + c0;
        #pragma unroll
        for (int q = 0; q < 4; ++q) {
            float4 f = *(const float4*)(vp + 4 * q);
            vfl[4*q+0]=f.x; vfl[4*q+1]=f.y; vfl[4*q+2]=f.z; vfl[4*q+3]=f.w;
        }
    }
    if (!FIRST && tid < 64) sTau[tid] = tauIn[(size_t)wg * 64 + tid];
    __syncthreads();

    const int w = tid >> 6, lid = tid & 63, lo4 = lid & 15, hi4 = lid >> 4;

    // ---- MM1: A = G rows (strip 16w), B = K rows; D[j,i] ----
    f32x4 acc[4] = {};
    #pragma unroll
    for (int ks = 0; ks < 2; ++ks) {
        short8v ah = ldfrag(sGh, 16 * w + lo4, hi4 + 4 * ks);
        short8v al = ldfrag(sGl, 16 * w + lo4, hi4 + 4 * ks);
        #pragma unroll
        for (int t = 0; t < 4; ++t) {
            short8v bh = ldfrag(sKh, 16 * t + lo4, hi4 + 4 * ks);
            short8v bl = ldfrag(sKl, 16 * t + lo4, hi4 + 4 * ks);
            MFMA(acc[t], ah, bh); MFMA(acc[t], ah, bl); MFMA(acc[t], al, bh);
        }
    }
    __syncthreads();   // all MM1 LDS reads done before right / V^T overwrite

    // ---- softmax over i (in-lane t, cross-lane lo4); write right hi/lo ----
    #pragma unroll
    for (int rr = 0; rr < 4; ++rr) {
        const int j = 16 * w + 4 * hi4 + rr;
        const float tv = FIRST ? 1.0f : sTau[j];
        const bool tz = !(tv > 1e-8f);
        const float tvi = tz ? 1.0f : (1.0f / tv);
        float lg[4];
        #pragma unroll
        for (int t = 0; t < 4; ++t) lg[t] = acc[t][rr] * tvi;
        float m = fmaxf(fmaxf(lg[0], lg[1]), fmaxf(lg[2], lg[3]));
        m = rmax16(m);
        float e[4], s = 0.f;
        #pragma unroll
        for (int t = 0; t < 4; ++t) { e[t] = __expf(lg[t] - m); s += e[t]; }
        s = rsum16(s);
        const float inv = 1.0f / s;
        float ap = 0.f;
        #pragma unroll
        for (int t = 0; t < 4; ++t) {
            const float rrv = tz ? (1.0f / 64.0f) : e[t] * inv;
            ap += (rrv > 0.f) ? rrv * __logf(rrv) : 0.f;
            const ushort hh = bf_rne(rrv);
            const ushort ll = bf_rne(rrv - bf2f(hh));
            const int idx = swz_idx(j, 16 * t + lo4);
            sGh[idx] = hh; sGl[idx] = ll;
        }
        ap = rsum16(ap);
        if (lo4 == 0) alphaOut[(size_t)wg * 64 + j] = ap;
    }
    if (LAST) {        // V^T into sK space (K row-major now dead)
        #pragma unroll
        for (int e = 0; e < 16; ++e) {
            const ushort hh = bf_rne(vfl[e]);
            const ushort ll = bf_rne(vfl[e] - bf2f(hh));
            const int jj = (e + r) & 15;
            // rotate iteration order instead: recompute for rotated element
            (void)hh; (void)ll; (void)jj;
        }
        ushort vh[16], vl[16];
        #pragma unroll
        for (int e = 0; e < 16; ++e) {
            vh[e] = bf_rne(vfl[e]);
            vl[e] = bf_rne(vfl[e] - bf2f(vh[e]));
        }
        #pragma unroll
        for (int e = 0; e < 16; ++e) {
            const int jj = (e + r) & 15;
            const int idx = swz_idx(c0 + jj, r);
            sKh[idx] = vh[jj]; sKl[idx] = vl[jj];
        }
    }
    __syncthreads();

    // ---- MM2: A = right rows, B = K (via K^T);  MM3 (LAST): B = V (via V^T) ----
    f32x4 acc2[4] = {};
    f32x4 acc3[4] = {};
    #pragma unroll
    for (int ks = 0; ks < 2; ++ks) {
        short8v ah = ldfrag(sGh, 16 * w + lo4, hi4 + 4 * ks);
        short8v al = ldfrag(sGl, 16 * w + lo4, hi4 + 4 * ks);
        #pragma unroll
        for (int t = 0; t < 4; ++t) {
            short8v bh = ldfrag(sTh, 16 * t + lo4, hi4 + 4 * ks);
            short8v bl = ldfrag(sTl, 16 * t + lo4, hi4 + 4 * ks);
            MFMA(acc2[t], ah, bh); MFMA(acc2[t], ah, bl); MFMA(acc2[t], al, bh);
            if (LAST) {
                short8v ch = ldfrag(sKh, 16 * t + lo4, hi4 + 4 * ks);
                short8v cl = ldfrag(sKl, 16 * t + lo4, hi4 + 4 * ks);
                MFMA(acc3[t], ah, ch); MFMA(acc3[t], ah, cl); MFMA(acc3[t], al, ch);
            }
        }
    }
    #pragma unroll
    for (int rr = 0; rr < 4; ++rr) {
        const int j = 16 * w + 4 * hi4 + rr;
        const size_t base = (size_t)h * 262144 + (size_t)j * 4096 + (size_t)k * 64;
        #pragma unroll
        for (int t = 0; t < 4; ++t) {
            Hm[base + 16 * t + lo4] = acc2[t][rr];
            if (LAST) Yout[base + 16 * t + lo4] = acc3[t][rr];
        }
    }
}

// One WG per (h,j).
// MM1: beta2[l,k] = sum_v q[l,v] Hm[k,v]; left = softmax_k(beta2 - alpha[k])
// !LAST: MM2: G[k,v] = sum_l left[l,k] q[l,v]; tau[k] = sum_l left[l,k] (ones-MFMA)
//  LAST: MM3: Z[l,v] = sum_k left[l,k] Y[k,v]
template<int LAST>
__global__ __launch_bounds__(256) void da_kernel(
    const float* __restrict__ Q,
    const float* __restrict__ HmIn,
    const float* __restrict__ alphaIn,
    const float* __restrict__ Yin,    // LAST only
    float* __restrict__ Gout,         // !LAST
    float* __restrict__ tauOut,       // !LAST
    float* __restrict__ Zout)         // LAST
{
    __shared__ __align__(16) ushort sQh[4096], sQl[4096];   // q rows (scaled)
    __shared__ __align__(16) ushort sHh[4096], sHl[4096];   // Hm rows -> left^T / left
    __shared__ __align__(16) ushort sTh[4096], sTl[4096];   // q^T (!LAST) / Y^T (LAST)
    __shared__ float sAl[64];

    const int wg = blockIdx.x, h = wg >> 6, j = wg & 63;
    const int tid = threadIdx.x;
    const int r = tid >> 2, c0 = (tid & 3) << 4;

    const float* qp = Q + (size_t)h * HEADQ + (size_t)r * 4096 + (size_t)j * 64 + c0;
    if (!LAST) stage16<true, true >(qp, 0.125f, sQh, sQl, sTh, sTl, r, c0);
    else       stage16<true, false>(qp, 0.125f, sQh, sQl, nullptr, nullptr, r, c0);
    const float* hp = HmIn + (size_t)wg * 4096 + r * 64 + c0;
    stage16<true, false>(hp, 1.f, sHh, sHl, nullptr, nullptr, r, c0);
    if (LAST) {
        const float* yp = Yin + (size_t)wg * 4096 + r * 64 + c0;
        stage16<false, true>(yp, 1.f, nullptr, nullptr, sTh, sTl, r, c0);
    }
    if (tid < 64) sAl[tid] = alphaIn[((size_t)h * 64 + tid) * 64 + j];
    __syncthreads();

    const int w = tid >> 6, lid = tid & 63, lo4 = lid & 15, hi4 = lid >> 4;

    // ---- MM1: A = q rows (strip 16w), B = Hm rows; D[l,k] ----
    f32x4 acc[4] = {};
    #pragma unroll
    for (int ks = 0; ks < 2; ++ks) {
        short8v ah = ldfrag(sQh, 16 * w + lo4, hi4 + 4 * ks);
        short8v al = ldfrag(sQl, 16 * w + lo4, hi4 + 4 * ks);
        #pragma unroll
        for (int t = 0; t < 4; ++t) {
            short8v bh = ldfrag(sHh, 16 * t + lo4, hi4 + 4 * ks);
            short8v bl = ldfrag(sHl, 16 * t + lo4, hi4 + 4 * ks);
            MFMA(acc[t], ah, bh); MFMA(acc[t], ah, bl); MFMA(acc[t], al, bh);
        }
    }
    __syncthreads();   // sH reads done before left overwrites it

    // ---- left = softmax over k of (beta2 - alpha[k]); write left(^T) hi/lo ----
    #pragma unroll
    for (int rr = 0; rr < 4; ++rr) {
        const int l = 16 * w + 4 * hi4 + rr;
        float lg[4];
        #pragma unroll
        for (int t = 0; t < 4; ++t) lg[t] = acc[t][rr] - sAl[16 * t + lo4];
        float m = fmaxf(fmaxf(lg[0], lg[1]), fmaxf(lg[2], lg[3]));
        m = rmax16(m);
        float e[4], s = 0.f;
        #pragma unroll
        for (int t = 0; t < 4; ++t) { e[t] = __expf(lg[t] - m); s += e[t]; }
        s = rsum16(s);
        const float inv = 1.0f / s;
        #pragma unroll
        for (int t = 0; t < 4; ++t) {
            const float lvv = e[t] * inv;
            const ushort hh = bf_rne(lvv);
            const ushort ll = bf_rne(lvv - bf2f(hh));
            int row, col;
            if (!LAST) { row = 16 * t + lo4; col = l; }        // left^T [k][l]
            else       { row = l;            col = 16 * t + lo4; } // left [l][k]
            const int idx = swz_idx(row, col);
            sHh[idx] = hh; sHl[idx] = ll;
        }
    }
    __syncthreads();

    if (!LAST) {
        // ---- MM2: A = left^T rows (k strip), B = q (via q^T); D[k,v]; tau via ones ----
        f32x4 acc2[4] = {};
        f32x4 tacc = {};
        short8v onesb;
        #pragma unroll
        for (int e = 0; e < 8; ++e) onesb[e] = (lo4 == 0) ? (short)0x3F80 : (short)0;
        #pragma unroll
        for (int ks = 0; ks < 2; ++ks) {
            short8v ah = ldfrag(sHh, 16 * w + lo4, hi4 + 4 * ks);
            short8v al = ldfrag(sHl, 16 * w + lo4, hi4 + 4 * ks);
            MFMA(tacc, ah, onesb); MFMA(tacc, al, onesb);
            #pragma unroll
            for (int t = 0; t < 4; ++t) {
                short8v bh = ldfrag(sTh, 16 * t + lo4, hi4 + 4 * ks);
                short8v bl = ldfrag(sTl, 16 * t + lo4, hi4 + 4 * ks);
                MFMA(acc2[t], ah, bh); MFMA(acc2[t], ah, bl); MFMA(acc2[t], al, bh);
            }
        }
        #pragma unroll
        for (int rr = 0; rr < 4; ++rr) {
            const int kk = 16 * w + 4 * hi4 + rr;
            const size_t gb = ((size_t)h * 64 + kk) * 4096 + (size_t)j * 64;
            #pragma unroll
            for (int t = 0; t < 4; ++t) Gout[gb + 16 * t + lo4] = acc2[t][rr];
            if (lo4 == 0) tauOut[((size_t)h * 64 + kk) * 64 + j] = tacc[rr];
        }
    } else {
        // ---- MM3: A = left rows (l strip), B = Y (via Y^T); D[l,v] ----
        f32x4 acc2[4] = {};
        #pragma unroll
        for (int ks = 0; ks < 2; ++ks) {
            short8v ah = ldfrag(sHh, 16 * w + lo4, hi4 + 4 * ks);
            short8v al = ldfrag(sHl, 16 * w + lo4, hi4 + 4 * ks);
            #pragma unroll
            for (int t = 0; t < 4; ++t) {
                short8v bh = ldfrag(sTh, 16 * t + lo4, hi4 + 4 * ks);
                short8v bl = ldfrag(sTl, 16 * t + lo4, hi4 + 4 * ks);
                MFMA(acc2[t], ah, bh); MFMA(acc2[t], ah, bl); MFMA(acc2[t], al, bh);
            }
        }
        #pragma unroll
        for (int rr = 0; rr < 4; ++rr) {
            const int l = 16 * w + 4 * hi4 + rr;
            const size_t zb = (size_t)h * HEADQ + (size_t)l * 4096 + (size_t)j * 64;
            #pragma unroll
            for (int t = 0; t < 4; ++t) Zout[zb + 16 * t + lo4] = acc2[t][rr];
        }
    }
}

} // namespace

extern "C" void kernel_launch(void* const* d_in, const int* in_sizes, int n_in,
                              void* d_out, int out_size, void* d_ws, size_t ws_size,
                              hipStream_t stream) {
    const float* Q = (const float*)d_in[0];
    const float* K = (const float*)d_in[1];
    const float* V = (const float*)d_in[2];
    float* out = (float*)d_out;

    char* ws = (char*)d_ws;
    const size_t MB = 1024 * 1024;
    float* G   = (float*)(ws);                  // 64 MiB (fallback: z staging)
    float* Hm  = (float*)(ws + 64 * MB);        // 64 MiB
    float* M   = (float*)(ws + 128 * MB);       //  1 MiB
    float* al  = (float*)(ws + 129 * MB);       //  1 MiB
    float* tau = (float*)(ws + 130 * MB);       //  1 MiB

    const bool bigws = ws_size >= (size_t)196 * MB;
    float* Ybuf = bigws ? (float*)(ws + 131 * MB) : out;   // Y staging
    float* Zdst = bigws ? out : G;                         // final z destination

    dim3 blk(256), grid(HEADS * 64);

    kmean_kernel<<<dim3(HEADS * 64), dim3(64), 0, stream>>>(Q, M);
    bc_kernel<1, 0><<<grid, blk, 0, stream>>>(M, K, nullptr, nullptr, Hm, al, nullptr);
    da_kernel<0>   <<<grid, blk, 0, stream>>>(Q, Hm, al, nullptr, G, tau, nullptr);
    bc_kernel<0, 0><<<grid, blk, 0, stream>>>(G, K, nullptr, tau, Hm, al, nullptr);
    da_kernel<0>   <<<grid, blk, 0, stream>>>(Q, Hm, al, nullptr, G, tau, nullptr);
    bc_kernel<0, 1><<<grid, blk, 0, stream>>>(G, K, V, tau, Hm, al, Ybuf);
    da_kernel<1>   <<<grid, blk, 0, stream>>>(Q, Hm, al, Ybuf, nullptr, nullptr, Zdst);
    if (!bigws)
        hipMemcpyAsync(d_out, G, MATF * sizeof(float), hipMemcpyDeviceToDevice, stream);
}

// Round 3
// 331.295 us; speedup vs baseline: 1.6081x; 1.1646x over previous
//
#include <hip/hip_runtime.h>

// SOBA-Monarch, B*H=64 heads, S=4096, D=64, nb=bs=64, pad=0, 3 steps.
// Round 3: packed hi/lo-bf16 u32 LDS tiles [64][68], conflict-free scatters,
// static-indexed staging (no scratch), producers emit packed intermediates.

namespace {

typedef __attribute__((ext_vector_type(8))) short short8v;
typedef __attribute__((ext_vector_type(4))) float f32x4;
typedef __attribute__((ext_vector_type(4))) uint uint4v;

constexpr int HEADS = 64;                        // B*H
constexpr size_t HEADQ = 262144;                 // 4096*64 elems per head
constexpr size_t MATF  = (size_t)HEADS * 262144; // elems in G/Hm/Y/z

#define MFMA(ACC, A, B) ACC = __builtin_amdgcn_mfma_f32_16x16x32_bf16(A, B, ACC, 0, 0, 0)

__device__ __forceinline__ float rmax16(float m) {
    m = fmaxf(m, __shfl_xor(m, 1));
    m = fmaxf(m, __shfl_xor(m, 2));
    m = fmaxf(m, __shfl_xor(m, 4));
    m = fmaxf(m, __shfl_xor(m, 8));
    return m;
}
__device__ __forceinline__ float rsum16(float s) {
    s += __shfl_xor(s, 1);
    s += __shfl_xor(s, 2);
    s += __shfl_xor(s, 4);
    s += __shfl_xor(s, 8);
    return s;
}

// pack f32 -> (hi bf16 in top 16 via RNE) | (lo bf16 of residual in bottom 16)
__device__ __forceinline__ uint packbf(float x) {
    uint u = __float_as_uint(x);
    uint hi = (u + 0x7FFFu + ((u >> 16) & 1u)) & 0xFFFF0000u;
    float d = x - __uint_as_float(hi);
    return hi | (__float_as_uint(d) >> 16);
}

// load an 8-elem MFMA fragment pair (hi,lo) from a packed tile row
__device__ __forceinline__ void fragpair(const uint* T, int row, int g8,
                                         short8v& h, short8v& l) {
    const uint* p = T + row * 68 + g8 * 8;
    uint4 a = *(const uint4*)(p);
    uint4 b = *(const uint4*)(p + 4);
    uint h01 = (a.x >> 16) | (a.y & 0xFFFF0000u);
    uint h23 = (a.z >> 16) | (a.w & 0xFFFF0000u);
    uint h45 = (b.x >> 16) | (b.y & 0xFFFF0000u);
    uint h67 = (b.z >> 16) | (b.w & 0xFFFF0000u);
    uint l01 = (a.x & 0xFFFFu) | (a.y << 16);
    uint l23 = (a.z & 0xFFFFu) | (a.w << 16);
    uint l45 = (b.x & 0xFFFFu) | (b.y << 16);
    uint l67 = (b.z & 0xFFFFu) | (b.w << 16);
    h = __builtin_bit_cast(short8v, (uint4v){h01, h23, h45, h67});
    l = __builtin_bit_cast(short8v, (uint4v){l01, l23, l45, l67});
}

// M[h][j][v] = packbf( (1/64) * sum_l Q[h][l*64+j][v] / 8 )
__global__ void kmean_kernel(const float* __restrict__ Q, uint* __restrict__ M) {
    const int wg = blockIdx.x;            // h*64 + j
    const int h  = wg >> 6, j = wg & 63;
    const int v  = threadIdx.x;           // 64 threads
    const float* base = Q + (size_t)h * HEADQ + (size_t)j * 64 + v;
    float acc = 0.f;
    #pragma unroll
    for (int l = 0; l < 64; ++l) acc += base[(size_t)l * 4096];
    M[(size_t)wg * 64 + v] = packbf(acc * (1.0f / 512.0f));
}

// One WG (256T) per (h,k).
// MM1: beta[j,i]=sum_v G[j,v]K[i,v]; right=softmax_i(beta/tau); alpha[j]=sum r log r
// MM2: Hm[j,v]=sum_i right[j,i]K[i,v];  LAST: Y[j,v]=sum_i right[j,i]V[i,v]
template<int FIRST, int LAST>
__global__ __launch_bounds__(256) void bc_kernel(
    const uint*  __restrict__ Gsrc,   // packed; FIRST ? M : G
    const float* __restrict__ Kmat,
    const float* __restrict__ Vmat,   // LAST only
    const float* __restrict__ tauIn,  // !FIRST only
    float* __restrict__ Hm,
    float* __restrict__ alphaOut,
    float* __restrict__ Yout)         // LAST only
{
    __shared__ uint sG[64 * 68];      // packed G rows -> right rows (reuse)
    __shared__ uint sK[64 * 68];      // packed K rows -> V^T (LAST, reuse)
    __shared__ uint sT[64 * 68];      // packed K^T [v][i]

    const int wg = blockIdx.x, h = wg >> 6, k = wg & 63;
    const int tid = threadIdx.x;
    const int r = tid & 63, c0 = (tid >> 6) << 4;

    { // stage G: pure copy (already packed)
        const uint* gp = Gsrc + (FIRST ? (size_t)h * 4096 : (size_t)wg * 4096) + r * 64 + c0;
        uint* d = sG + r * 68 + c0;
        #pragma unroll
        for (int q = 0; q < 4; ++q) *(uint4*)(d + 4 * q) = *(const uint4*)(gp + 4 * q);
    }
    { // stage K: pack once -> row tile + transposed scatter (row-uniform, CF)
        const float* kp = Kmat + (size_t)h * HEADQ + (size_t)k * 4096 + r * 64 + c0;
        uint pk[16];
        #pragma unroll
        for (int q = 0; q < 4; ++q) {
            float4 f = *(const float4*)(kp + 4 * q);
            pk[4*q+0] = packbf(f.x); pk[4*q+1] = packbf(f.y);
            pk[4*q+2] = packbf(f.z); pk[4*q+3] = packbf(f.w);
        }
        uint* d = sK + r * 68 + c0;
        #pragma unroll
        for (int q = 0; q < 4; ++q)
            *(uint4*)(d + 4 * q) = *(const uint4*)(&pk[4 * q]);
        #pragma unroll
        for (int e = 0; e < 16; ++e) sT[(c0 + e) * 68 + r] = pk[e];
    }
    float vf[16];
    if (LAST) {
        const float* vp = Vmat + (size_t)h * HEADQ + (size_t)k * 4096 + r * 64 + c0;
        #pragma unroll
        for (int q = 0; q < 4; ++q) {
            float4 f = *(const float4*)(vp + 4 * q);
            vf[4*q+0] = f.x; vf[4*q+1] = f.y; vf[4*q+2] = f.z; vf[4*q+3] = f.w;
        }
    }
    __syncthreads();

    const int w = tid >> 6, lo4 = tid & 15, hi4 = (tid >> 4) & 3;

    // ---- MM1: A = G rows (strip 16w), B = K rows; D[j,i] ----
    f32x4 acc[4] = {};
    #pragma unroll
    for (int ks = 0; ks < 2; ++ks) {
        short8v ah, al; fragpair(sG, 16 * w + lo4, hi4 + 4 * ks, ah, al);
        #pragma unroll
        for (int t = 0; t < 4; ++t) {
            short8v bh, bl; fragpair(sK, 16 * t + lo4, hi4 + 4 * ks, bh, bl);
            MFMA(acc[t], ah, bh); MFMA(acc[t], ah, bl); MFMA(acc[t], al, bh);
        }
    }
    __syncthreads();   // MM1 LDS reads done before right / V^T overwrite

    float tvv[4];
    #pragma unroll
    for (int rr = 0; rr < 4; ++rr)
        tvv[rr] = FIRST ? 1.0f : tauIn[(size_t)wg * 64 + 16 * w + 4 * hi4 + rr];

    // ---- softmax over i (in-lane t, cross-lane lo4); write right packed ----
    #pragma unroll
    for (int rr = 0; rr < 4; ++rr) {
        const int j = 16 * w + 4 * hi4 + rr;
        const bool tz = !(tvv[rr] > 1e-8f);
        const float tvi = tz ? 1.0f : (1.0f / tvv[rr]);
        float lg[4];
        #pragma unroll
        for (int t = 0; t < 4; ++t) lg[t] = acc[t][rr] * tvi;
        float m = fmaxf(fmaxf(lg[0], lg[1]), fmaxf(lg[2], lg[3]));
        m = rmax16(m);
        float e[4], s = 0.f;
        #pragma unroll
        for (int t = 0; t < 4; ++t) { e[t] = __expf(lg[t] - m); s += e[t]; }
        s = rsum16(s);
        const float inv = 1.0f / s;
        float ap = 0.f;
        #pragma unroll
        for (int t = 0; t < 4; ++t) {
            const float rrv = tz ? (1.0f / 64.0f) : e[t] * inv;
            ap += (rrv > 0.f) ? rrv * __logf(rrv) : 0.f;
            sG[j * 68 + 16 * t + lo4] = packbf(rrv);
        }
        ap = rsum16(ap);
        if (lo4 == 0) alphaOut[(size_t)wg * 64 + j] = ap;
    }
    if (LAST) {        // V^T packed into sK space (row-uniform scatter, CF)
        #pragma unroll
        for (int e = 0; e < 16; ++e) sK[(c0 + e) * 68 + r] = packbf(vf[e]);
    }
    __syncthreads();

    // ---- MM2: A = right rows, B = K^T;  MM3 (LAST): B = V^T ----
    f32x4 acc2[4] = {};
    f32x4 acc3[4] = {};
    #pragma unroll
    for (int ks = 0; ks < 2; ++ks) {
        short8v ah, al; fragpair(sG, 16 * w + lo4, hi4 + 4 * ks, ah, al);
        #pragma unroll
        for (int t = 0; t < 4; ++t) {
            short8v bh, bl; fragpair(sT, 16 * t + lo4, hi4 + 4 * ks, bh, bl);
            MFMA(acc2[t], ah, bh); MFMA(acc2[t], ah, bl); MFMA(acc2[t], al, bh);
            if (LAST) {
                short8v ch, cl; fragpair(sK, 16 * t + lo4, hi4 + 4 * ks, ch, cl);
                MFMA(acc3[t], ah, ch); MFMA(acc3[t], ah, cl); MFMA(acc3[t], al, ch);
            }
        }
    }
    #pragma unroll
    for (int rr = 0; rr < 4; ++rr) {
        const int j = 16 * w + 4 * hi4 + rr;
        const size_t base = (size_t)h * 262144 + (size_t)j * 4096 + (size_t)k * 64;
        #pragma unroll
        for (int t = 0; t < 4; ++t) {
            Hm[base + 16 * t + lo4] = acc2[t][rr];
            if (LAST) Yout[base + 16 * t + lo4] = acc3[t][rr];
        }
    }
}

// One WG per (h,j).
// MM1: beta2[l,k]=sum_v q[l,v]Hm[k,v]; left=softmax_k(beta2-alpha[k])
// !LAST: MM2: G[k,v]=sum_l left[l,k]q[l,v] (packed out); tau[k] via ones-MFMA
//  LAST: MM3: Z[l,v]=sum_k left[l,k]Y[k,v]
template<int LAST>
__global__ __launch_bounds__(256) void da_kernel(
    const float* __restrict__ Q,
    const float* __restrict__ HmIn,
    const float* __restrict__ alphaIn,
    const float* __restrict__ Yin,    // LAST only
    uint*  __restrict__ Gout,         // !LAST (packed)
    float* __restrict__ tauOut,       // !LAST
    float* __restrict__ Zout)         // LAST
{
    __shared__ uint sQ[64 * 68];      // packed scaled q rows
    __shared__ uint sH[64 * 68];      // packed Hm rows -> left^T / left (reuse)
    __shared__ uint sT[64 * 68];      // packed q^T (!LAST) / Y^T (LAST)

    const int wg = blockIdx.x, h = wg >> 6, j = wg & 63;
    const int tid = threadIdx.x;
    const int r = tid & 63, c0 = (tid >> 6) << 4;

    { // stage q (x0.125): pack once -> rows (+ q^T scatter if !LAST)
        const float* qp = Q + (size_t)h * HEADQ + (size_t)r * 4096 + (size_t)j * 64 + c0;
        uint pq[16];
        #pragma unroll
        for (int q = 0; q < 4; ++q) {
            float4 f = *(const float4*)(qp + 4 * q);
            pq[4*q+0] = packbf(f.x * 0.125f); pq[4*q+1] = packbf(f.y * 0.125f);
            pq[4*q+2] = packbf(f.z * 0.125f); pq[4*q+3] = packbf(f.w * 0.125f);
        }
        uint* d = sQ + r * 68 + c0;
        #pragma unroll
        for (int q = 0; q < 4; ++q)
            *(uint4*)(d + 4 * q) = *(const uint4*)(&pq[4 * q]);
        if (!LAST) {
            #pragma unroll
            for (int e = 0; e < 16; ++e) sT[(c0 + e) * 68 + r] = pq[e];
        }
    }
    { // stage Hm rows (f32 -> packed)
        const float* hp = HmIn + (size_t)wg * 4096 + r * 64 + c0;
        uint ph[16];
        #pragma unroll
        for (int q = 0; q < 4; ++q) {
            float4 f = *(const float4*)(hp + 4 * q);
            ph[4*q+0] = packbf(f.x); ph[4*q+1] = packbf(f.y);
            ph[4*q+2] = packbf(f.z); ph[4*q+3] = packbf(f.w);
        }
        uint* d = sH + r * 68 + c0;
        #pragma unroll
        for (int q = 0; q < 4; ++q)
            *(uint4*)(d + 4 * q) = *(const uint4*)(&ph[4 * q]);
    }
    if (LAST) { // stage Y^T (f32 -> packed scatter, row-uniform CF)
        const float* yp = Yin + (size_t)wg * 4096 + r * 64 + c0;
        float yf[16];
        #pragma unroll
        for (int q = 0; q < 4; ++q) {
            float4 f = *(const float4*)(yp + 4 * q);
            yf[4*q+0] = f.x; yf[4*q+1] = f.y; yf[4*q+2] = f.z; yf[4*q+3] = f.w;
        }
        #pragma unroll
        for (int e = 0; e < 16; ++e) sT[(c0 + e) * 68 + r] = packbf(yf[e]);
    }
    __syncthreads();

    const int w = tid >> 6, lo4 = tid & 15, hi4 = (tid >> 4) & 3;

    // ---- MM1: A = q rows (strip 16w), B = Hm rows; D[l,k] ----
    f32x4 acc[4] = {};
    #pragma unroll
    for (int ks = 0; ks < 2; ++ks) {
        short8v ah, al; fragpair(sQ, 16 * w + lo4, hi4 + 4 * ks, ah, al);
        #pragma unroll
        for (int t = 0; t < 4; ++t) {
            short8v bh, bl; fragpair(sH, 16 * t + lo4, hi4 + 4 * ks, bh, bl);
            MFMA(acc[t], ah, bh); MFMA(acc[t], ah, bl); MFMA(acc[t], al, bh);
        }
    }
    __syncthreads();   // sH reads done before left overwrites it

    float av[4];
    #pragma unroll
    for (int t = 0; t < 4; ++t)
        av[t] = alphaIn[((size_t)h * 64 + 16 * t + lo4) * 64 + j];

    // ---- left = softmax over k of (beta2 - alpha[k]); packed write ----
    #pragma unroll
    for (int rr = 0; rr < 4; ++rr) {
        const int l = 16 * w + 4 * hi4 + rr;
        float lg[4];
        #pragma unroll
        for (int t = 0; t < 4; ++t) lg[t] = acc[t][rr] - av[t];
        float m = fmaxf(fmaxf(lg[0], lg[1]), fmaxf(lg[2], lg[3]));
        m = rmax16(m);
        float e[4], s = 0.f;
        #pragma unroll
        for (int t = 0; t < 4; ++t) { e[t] = __expf(lg[t] - m); s += e[t]; }
        s = rsum16(s);
        const float inv = 1.0f / s;
        #pragma unroll
        for (int t = 0; t < 4; ++t) {
            const uint pv = packbf(e[t] * inv);
            if (!LAST) sH[(16 * t + lo4) * 68 + l] = pv;   // left^T [k][l]
            else       sH[l * 68 + 16 * t + lo4] = pv;     // left [l][k]
        }
    }
    __syncthreads();

    if (!LAST) {
        // ---- MM2: A = left^T rows (k strip), B = q^T; tau via ones-B ----
        f32x4 acc2[4] = {};
        f32x4 tacc = {};
        short8v onesb;
        #pragma unroll
        for (int e = 0; e < 8; ++e) onesb[e] = (lo4 == 0) ? (short)0x3F80 : (short)0;
        #pragma unroll
        for (int ks = 0; ks < 2; ++ks) {
            short8v ah, al; fragpair(sH, 16 * w + lo4, hi4 + 4 * ks, ah, al);
            MFMA(tacc, ah, onesb); MFMA(tacc, al, onesb);
            #pragma unroll
            for (int t = 0; t < 4; ++t) {
                short8v bh, bl; fragpair(sT, 16 * t + lo4, hi4 + 4 * ks, bh, bl);
                MFMA(acc2[t], ah, bh); MFMA(acc2[t], ah, bl); MFMA(acc2[t], al, bh);
            }
        }
        #pragma unroll
        for (int rr = 0; rr < 4; ++rr) {
            const int kq = 16 * w + 4 * hi4 + rr;
            const size_t gb = ((size_t)h * 64 + kq) * 4096 + (size_t)j * 64;
            #pragma unroll
            for (int t = 0; t < 4; ++t) Gout[gb + 16 * t + lo4] = packbf(acc2[t][rr]);
            if (lo4 == 0) tauOut[((size_t)h * 64 + kq) * 64 + j] = tacc[rr];
        }
    } else {
        // ---- MM3: A = left rows (l strip), B = Y^T; D[l,v] ----
        f32x4 acc2[4] = {};
        #pragma unroll
        for (int ks = 0; ks < 2; ++ks) {
            short8v ah, al; fragpair(sH, 16 * w + lo4, hi4 + 4 * ks, ah, al);
            #pragma unroll
            for (int t = 0; t < 4; ++t) {
                short8v bh, bl; fragpair(sT, 16 * t + lo4, hi4 + 4 * ks, bh, bl);
                MFMA(acc2[t], ah, bh); MFMA(acc2[t], ah, bl); MFMA(acc2[t], al, bh);
            }
        }
        #pragma unroll
        for (int rr = 0; rr < 4; ++rr) {
            const int l = 16 * w + 4 * hi4 + rr;
            const size_t zb = (size_t)h * HEADQ + (size_t)l * 4096 + (size_t)j * 64;
            #pragma unroll
            for (int t = 0; t < 4; ++t) Zout[zb + 16 * t + lo4] = acc2[t][rr];
        }
    }
}

} // namespace

extern "C" void kernel_launch(void* const* d_in, const int* in_sizes, int n_in,
                              void* d_out, int out_size, void* d_ws, size_t ws_size,
                              hipStream_t stream) {
    const float* Q = (const float*)d_in[0];
    const float* K = (const float*)d_in[1];
    const float* V = (const float*)d_in[2];
    float* out = (float*)d_out;

    char* ws = (char*)d_ws;
    const size_t MB = 1024 * 1024;
    uint*  G   = (uint*)(ws);                   // 64 MiB packed (fallback: z staging)
    float* Hm  = (float*)(ws + 64 * MB);        // 64 MiB f32
    uint*  M   = (uint*)(ws + 128 * MB);        //  1 MiB packed
    float* al  = (float*)(ws + 129 * MB);       //  1 MiB
    float* tau = (float*)(ws + 130 * MB);       //  1 MiB

    const bool bigws = ws_size >= (size_t)196 * MB;
    float* Ybuf = bigws ? (float*)(ws + 131 * MB) : out;   // Y staging
    float* Zdst = bigws ? out : (float*)G;                 // final z destination

    dim3 blk(256), grid(HEADS * 64);

    kmean_kernel<<<dim3(HEADS * 64), dim3(64), 0, stream>>>(Q, M);
    bc_kernel<1, 0><<<grid, blk, 0, stream>>>(M, K, nullptr, nullptr, Hm, al, nullptr);
    da_kernel<0>   <<<grid, blk, 0, stream>>>(Q, Hm, al, nullptr, G, tau, nullptr);
    bc_kernel<0, 0><<<grid, blk, 0, stream>>>(G, K, nullptr, tau, Hm, al, nullptr);
    da_kernel<0>   <<<grid, blk, 0, stream>>>(Q, Hm, al, nullptr, G, tau, nullptr);
    bc_kernel<0, 1><<<grid, blk, 0, stream>>>(G, K, V, tau, Hm, al, Ybuf);
    da_kernel<1>   <<<grid, blk, 0, stream>>>(Q, Hm, al, Ybuf, nullptr, nullptr, Zdst);
    if (!bigws)
        hipMemcpyAsync(d_out, G, MATF * sizeof(float), hipMemcpyDeviceToDevice, stream);
}

// Round 4
// 305.503 us; speedup vs baseline: 1.7438x; 1.0844x over previous
//
#include <hip/hip_runtime.h>

// SOBA-Monarch, B*H=64 heads, S=4096, D=64, nb=bs=64, pad=0, 3 steps.
// Round 4: split hi/lo ushort LDS tiles [64][72] (raw b128 frag loads),
// 2-region LDS (36.9KB -> 4 WG/CU) via in-place transposes from registers,
// producer-contiguous global layouts + LDS-staged coalesced uint4 flushes.
// Layouts: G [h][j][k][v] u32 | Hm [h][k][j][v] u32 | Y [h][k][j][v] u32
//          alpha [h][j][k] f32 | tau [h][k][j] f32 | M [h][j][v] u32

namespace {

typedef __attribute__((ext_vector_type(8))) short short8v;
typedef __attribute__((ext_vector_type(4))) float f32x4;

constexpr int HEADS = 64;
constexpr size_t HEADQ = 262144;                 // 4096*64 per head
constexpr size_t MATF  = (size_t)HEADS * 262144;

#define MFMA(ACC, A, B) ACC = __builtin_amdgcn_mfma_f32_16x16x32_bf16(A, B, ACC, 0, 0, 0)
#define LD8(arr, row, g8) (*(const short8v*)((arr) + (row) * 72 + (g8) * 8))

__device__ __forceinline__ float rmax16(float m) {
    m = fmaxf(m, __shfl_xor(m, 1));
    m = fmaxf(m, __shfl_xor(m, 2));
    m = fmaxf(m, __shfl_xor(m, 4));
    m = fmaxf(m, __shfl_xor(m, 8));
    return m;
}
__device__ __forceinline__ float rsum16(float s) {
    s += __shfl_xor(s, 1);
    s += __shfl_xor(s, 2);
    s += __shfl_xor(s, 4);
    s += __shfl_xor(s, 8);
    return s;
}

__device__ __forceinline__ void bfsplit(float x, ushort& h, ushort& l) {
    uint u = __float_as_uint(x);
    uint hi = (u + 0x7FFFu + ((u >> 16) & 1u)) & 0xFFFF0000u;
    h = (ushort)(hi >> 16);
    l = (ushort)(__float_as_uint(x - __uint_as_float(hi)) >> 16);
}
__device__ __forceinline__ uint packbf(float x) {
    uint u = __float_as_uint(x);
    uint hi = (u + 0x7FFFu + ((u >> 16) & 1u)) & 0xFFFF0000u;
    return hi | (__float_as_uint(x - __uint_as_float(hi)) >> 16);
}

struct Frag16 { short8v h0, h1, l0, l1; };   // 16 elems: hi[0..15], lo[0..15]

__device__ __forceinline__ Frag16 load_packed16(const uint* p) {
    Frag16 f;
    #pragma unroll
    for (int q = 0; q < 4; ++q) {
        uint4 a = *(const uint4*)(p + 4 * q);
        uint vv[4] = {a.x, a.y, a.z, a.w};
        #pragma unroll
        for (int e = 0; e < 4; ++e) {
            const int i = 4 * q + e;
            const ushort hh = (ushort)(vv[e] >> 16), ll = (ushort)(vv[e] & 0xFFFFu);
            if (i < 8) { f.h0[i] = (short)hh; f.l0[i] = (short)ll; }
            else       { f.h1[i - 8] = (short)hh; f.l1[i - 8] = (short)ll; }
        }
    }
    return f;
}
__device__ __forceinline__ Frag16 load_f32x16(const float* p, float s) {
    Frag16 f;
    #pragma unroll
    for (int q = 0; q < 4; ++q) {
        float4 a = *(const float4*)(p + 4 * q);
        float vv[4] = {a.x * s, a.y * s, a.z * s, a.w * s};
        #pragma unroll
        for (int e = 0; e < 4; ++e) {
            const int i = 4 * q + e;
            ushort hh, ll; bfsplit(vv[e], hh, ll);
            if (i < 8) { f.h0[i] = (short)hh; f.l0[i] = (short)ll; }
            else       { f.h1[i - 8] = (short)hh; f.l1[i - 8] = (short)ll; }
        }
    }
    return f;
}
__device__ __forceinline__ void store_rows(ushort* H, ushort* L, int r, int c0,
                                           const Frag16& f) {
    *(short8v*)(H + r * 72 + c0)     = f.h0;
    *(short8v*)(H + r * 72 + c0 + 8) = f.h1;
    *(short8v*)(L + r * 72 + c0)     = f.l0;
    *(short8v*)(L + r * 72 + c0 + 8) = f.l1;
}
__device__ __forceinline__ void scatter_tr(ushort* H, ushort* L, int r, int c0,
                                           const Frag16& f) {
    #pragma unroll
    for (int e = 0; e < 8; ++e) {
        H[(c0 + e) * 72 + r] = (ushort)f.h0[e];
        L[(c0 + e) * 72 + r] = (ushort)f.l0[e];
    }
    #pragma unroll
    for (int e = 0; e < 8; ++e) {
        H[(c0 + 8 + e) * 72 + r] = (ushort)f.h1[e];
        L[(c0 + 8 + e) * 72 + r] = (ushort)f.l1[e];
    }
}

// readback staged [64][68] u32 tile -> contiguous 16KB global block (uint4, 1KB/wave-instr)
__device__ __forceinline__ void flush_u32(const uint* OS, uint* g, int tid) {
    #pragma unroll
    for (int q = 0; q < 4; ++q) {
        const int off = tid * 4 + q * 1024;
        uint4 v = *(const uint4*)(OS + (off >> 6) * 68 + (off & 63));
        *(uint4*)(g + off) = v;
    }
}

__device__ __forceinline__ void mmstep(const ushort* AH, const ushort* AL,
                                       const ushort* BH, const ushort* BL,
                                       int w, int lo4, int hi4, f32x4 acc[4]) {
    #pragma unroll
    for (int ks = 0; ks < 2; ++ks) {
        short8v ah = LD8(AH, 16 * w + lo4, hi4 + 4 * ks);
        short8v al = LD8(AL, 16 * w + lo4, hi4 + 4 * ks);
        #pragma unroll
        for (int t = 0; t < 4; ++t) {
            short8v bh = LD8(BH, 16 * t + lo4, hi4 + 4 * ks);
            short8v bl = LD8(BL, 16 * t + lo4, hi4 + 4 * ks);
            MFMA(acc[t], ah, bh); MFMA(acc[t], ah, bl); MFMA(acc[t], al, bh);
        }
    }
}

// M[h][j][v] = packbf( (1/512) * sum_l Q[h][l*64+j][v] )
__global__ void kmean_kernel(const float* __restrict__ Q, uint* __restrict__ M) {
    const int wg = blockIdx.x;            // h*64 + j
    const int h  = wg >> 6, j = wg & 63;
    const int v  = threadIdx.x;           // 64 threads
    const float* base = Q + (size_t)h * HEADQ + (size_t)j * 64 + v;
    float acc = 0.f;
    #pragma unroll
    for (int l = 0; l < 64; ++l) acc += base[(size_t)l * 4096];
    M[(size_t)wg * 64 + v] = packbf(acc * (1.0f / 512.0f));
}

// One WG (256T) per (h,k).
// MM1: beta[j,i]=sum_v G[j,v]K[i,v]; right=softmax_i(beta/tau); alpha[j]=sum r log r
// MM2: Hm[j,v]=sum_i right[j,i]K[i,v];  LAST: Y[j,v]=sum_i right[j,i]V[i,v]
template<int FIRST, int LAST>
__global__ __launch_bounds__(256) void bc_kernel(
    const uint*  __restrict__ Gsrc,   // FIRST ? M[h][j][v] : G[h][j][k][v]
    const float* __restrict__ Kmat,
    const float* __restrict__ Vmat,   // LAST only
    const float* __restrict__ tauIn,  // !FIRST only, [h][k][j]
    uint*  __restrict__ HmOut,        // [h][k][j][v] packed
    float* __restrict__ alphaOut,     // [h][j][k]
    uint*  __restrict__ Yout)         // LAST only, [h][k][j][v] packed
{
    __shared__ uint SM[9216];                       // 36864 B
    ushort* Ah = (ushort*)SM;        ushort* Al = Ah + 4608;   // region A
    ushort* Bh = (ushort*)(SM + 4608); ushort* Bl = Bh + 4608; // region B
    uint* OS  = SM + 4608;   // staging aliases B
    uint* OS2 = SM;          // staging aliases A (LAST)

    const int wg = blockIdx.x, h = wg >> 6, k = wg & 63;
    const int tid = threadIdx.x, r = tid & 63, c0 = (tid >> 6) << 4;

    { // stage G rows -> A (pure split copy)
        const uint* gp = FIRST ? (Gsrc + ((size_t)h * 64 + r) * 64 + c0)
                               : (Gsrc + ((size_t)h * 64 + r) * 4096 + (size_t)k * 64 + c0);
        Frag16 fg = load_packed16(gp);
        store_rows(Ah, Al, r, c0, fg);
    }
    // stage K rows -> B, keep regs for K^T
    Frag16 fk = load_f32x16(Kmat + (size_t)h * HEADQ + (size_t)k * 4096 + r * 64 + c0, 1.f);
    store_rows(Bh, Bl, r, c0, fk);
    Frag16 fv;
    if (LAST)
        fv = load_f32x16(Vmat + (size_t)h * HEADQ + (size_t)k * 4096 + r * 64 + c0, 1.f);

    const int w = tid >> 6, lo4 = tid & 15, hi4 = (tid >> 4) & 3;
    float tvv[4];
    #pragma unroll
    for (int rr = 0; rr < 4; ++rr)
        tvv[rr] = FIRST ? 1.f : tauIn[((size_t)h * 64 + k) * 64 + 16 * w + 4 * hi4 + rr];
    __syncthreads();

    f32x4 acc[4] = {};
    mmstep(Ah, Al, Bh, Bl, w, lo4, hi4, acc);       // D[j,i]
    __syncthreads();

    // softmax over i; scatter right -> A (rows), K^T -> B
    #pragma unroll
    for (int rr = 0; rr < 4; ++rr) {
        const int j = 16 * w + 4 * hi4 + rr;
        const bool tz = !(tvv[rr] > 1e-8f);
        const float tvi = tz ? 1.f : 1.f / tvv[rr];
        float lg[4];
        #pragma unroll
        for (int t = 0; t < 4; ++t) lg[t] = acc[t][rr] * tvi;
        float m = rmax16(fmaxf(fmaxf(lg[0], lg[1]), fmaxf(lg[2], lg[3])));
        float e[4], s = 0.f;
        #pragma unroll
        for (int t = 0; t < 4; ++t) { e[t] = __expf(lg[t] - m); s += e[t]; }
        s = rsum16(s);
        const float inv = 1.f / s;
        float ap = 0.f;
        #pragma unroll
        for (int t = 0; t < 4; ++t) {
            const float rv = tz ? (1.f / 64.f) : e[t] * inv;
            ap += (rv > 0.f) ? rv * __logf(rv) : 0.f;
            ushort hh, ll; bfsplit(rv, hh, ll);
            Ah[j * 72 + 16 * t + lo4] = hh;
            Al[j * 72 + 16 * t + lo4] = ll;
        }
        ap = rsum16(ap);
        if (lo4 == 0) alphaOut[((size_t)h * 64 + j) * 64 + k] = ap;
    }
    scatter_tr(Bh, Bl, r, c0, fk);                  // K^T over dead K rows
    __syncthreads();

    f32x4 acc2[4] = {};
    mmstep(Ah, Al, Bh, Bl, w, lo4, hi4, acc2);      // Hm[j,v]: A=right, B=K^T
    f32x4 acc3[4] = {};
    if (LAST) {
        __syncthreads();
        scatter_tr(Bh, Bl, r, c0, fv);              // V^T over dead K^T
        __syncthreads();
        mmstep(Ah, Al, Bh, Bl, w, lo4, hi4, acc3);  // Y[j,v]: A=right, B=V^T
    }
    __syncthreads();

    #pragma unroll
    for (int rr = 0; rr < 4; ++rr) {                // stage Hm packed -> OS(B)
        const int j = 16 * w + 4 * hi4 + rr;
        #pragma unroll
        for (int t = 0; t < 4; ++t) OS[j * 68 + 16 * t + lo4] = packbf(acc2[t][rr]);
    }
    if (LAST) {
        #pragma unroll
        for (int rr = 0; rr < 4; ++rr) {            // stage Y packed -> OS2(A)
            const int j = 16 * w + 4 * hi4 + rr;
            #pragma unroll
            for (int t = 0; t < 4; ++t) OS2[j * 68 + 16 * t + lo4] = packbf(acc3[t][rr]);
        }
    }
    __syncthreads();
    flush_u32(OS, HmOut + (size_t)wg * 4096, tid);
    if (LAST) flush_u32(OS2, Yout + (size_t)wg * 4096, tid);
}

// One WG per (h,j).
// MM1: beta2[l,k]=sum_v q[l,v]Hm[k,v]; left=softmax_k(beta2-alpha[k])
// !LAST: G[k,v]=sum_l left[l,k]q[l,v] (packed); tau[k] via ones-MFMA
//  LAST: Z[l,v]=sum_k left[l,k]Y[k,v]
template<int LAST>
__global__ __launch_bounds__(256) void da_kernel(
    const float* __restrict__ Q,
    const uint*  __restrict__ HmIn,   // [h][k][j][v] packed
    const float* __restrict__ alphaIn,// [h][j][k]
    const uint*  __restrict__ Yin,    // LAST only, [h][k][j][v] packed
    uint*  __restrict__ Gout,         // !LAST, [h][j][k][v] packed
    float* __restrict__ tauOut,       // !LAST, [h][k][j]
    float* __restrict__ Zout)         // LAST
{
    __shared__ uint SM[9216];
    ushort* Ah = (ushort*)SM;        ushort* Al = Ah + 4608;   // q rows -> q^T / Y^T
    ushort* Bh = (ushort*)(SM + 4608); ushort* Bl = Bh + 4608; // Hm rows -> left
    uint*  OSu = SM + 4608;
    float* OSf = (float*)(SM + 4608);

    const int wg = blockIdx.x, h = wg >> 6, j = wg & 63;
    const int tid = threadIdx.x, r = tid & 63, c0 = (tid >> 6) << 4;

    Frag16 fq = load_f32x16(Q + (size_t)h * HEADQ + (size_t)r * 4096 + (size_t)j * 64 + c0,
                            0.125f);
    store_rows(Ah, Al, r, c0, fq);
    {
        Frag16 fh = load_packed16(HmIn + ((size_t)h * 64 + r) * 4096 + (size_t)j * 64 + c0);
        store_rows(Bh, Bl, r, c0, fh);
    }
    Frag16 fy;
    if (LAST)
        fy = load_packed16(Yin + ((size_t)h * 64 + r) * 4096 + (size_t)j * 64 + c0);

    const int w = tid >> 6, lo4 = tid & 15, hi4 = (tid >> 4) & 3;
    float av[4];
    #pragma unroll
    for (int t = 0; t < 4; ++t)
        av[t] = alphaIn[((size_t)h * 64 + j) * 64 + 16 * t + lo4];
    __syncthreads();

    f32x4 acc[4] = {};
    mmstep(Ah, Al, Bh, Bl, w, lo4, hi4, acc);       // D[l,k]: A=q rows, B=Hm rows
    __syncthreads();

    // left = softmax over k; scatter left(^T) -> B; q^T / Y^T -> A
    #pragma unroll
    for (int rr = 0; rr < 4; ++rr) {
        const int l = 16 * w + 4 * hi4 + rr;
        float lg[4];
        #pragma unroll
        for (int t = 0; t < 4; ++t) lg[t] = acc[t][rr] - av[t];
        float m = rmax16(fmaxf(fmaxf(lg[0], lg[1]), fmaxf(lg[2], lg[3])));
        float e[4], s = 0.f;
        #pragma unroll
        for (int t = 0; t < 4; ++t) { e[t] = __expf(lg[t] - m); s += e[t]; }
        s = rsum16(s);
        const float inv = 1.f / s;
        #pragma unroll
        for (int t = 0; t < 4; ++t) {
            const float lv = e[t] * inv;
            ushort hh, ll; bfsplit(lv, hh, ll);
            if (!LAST) { Bh[(16 * t + lo4) * 72 + l] = hh; Bl[(16 * t + lo4) * 72 + l] = ll; }
            else       { Bh[l * 72 + 16 * t + lo4] = hh; Bl[l * 72 + 16 * t + lo4] = ll; }
        }
    }
    if (!LAST) scatter_tr(Ah, Al, r, c0, fq);       // q^T over dead q rows
    else       scatter_tr(Ah, Al, r, c0, fy);       // Y^T over dead q rows
    __syncthreads();

    if (!LAST) {
        f32x4 acc2[4] = {};
        f32x4 tacc = {};
        short8v onesb;
        #pragma unroll
        for (int e2 = 0; e2 < 8; ++e2) onesb[e2] = (lo4 == 0) ? (short)0x3F80 : (short)0;
        #pragma unroll
        for (int ks = 0; ks < 2; ++ks) {
            short8v ah = LD8(Bh, 16 * w + lo4, hi4 + 4 * ks);  // left^T rows (k strip)
            short8v al = LD8(Bl, 16 * w + lo4, hi4 + 4 * ks);
            MFMA(tacc, ah, onesb); MFMA(tacc, al, onesb);
            #pragma unroll
            for (int t = 0; t < 4; ++t) {
                short8v bh = LD8(Ah, 16 * t + lo4, hi4 + 4 * ks); // q^T rows (v)
                short8v bl = LD8(Al, 16 * t + lo4, hi4 + 4 * ks);
                MFMA(acc2[t], ah, bh); MFMA(acc2[t], ah, bl); MFMA(acc2[t], al, bh);
            }
        }
        __syncthreads();
        #pragma unroll
        for (int rr = 0; rr < 4; ++rr) {            // stage G packed -> OSu(B)
            const int kq = 16 * w + 4 * hi4 + rr;
            if (lo4 == 0) tauOut[((size_t)h * 64 + kq) * 64 + j] = tacc[rr];
            #pragma unroll
            for (int t = 0; t < 4; ++t) OSu[kq * 68 + 16 * t + lo4] = packbf(acc2[t][rr]);
        }
        __syncthreads();
        flush_u32(OSu, Gout + (size_t)wg * 4096, tid);
    } else {
        f32x4 acc2[4] = {};
        #pragma unroll
        for (int ks = 0; ks < 2; ++ks) {
            short8v ah = LD8(Bh, 16 * w + lo4, hi4 + 4 * ks);  // left rows (l strip)
            short8v al = LD8(Bl, 16 * w + lo4, hi4 + 4 * ks);
            #pragma unroll
            for (int t = 0; t < 4; ++t) {
                short8v bh = LD8(Ah, 16 * t + lo4, hi4 + 4 * ks); // Y^T rows (v)
                short8v bl = LD8(Al, 16 * t + lo4, hi4 + 4 * ks);
                MFMA(acc2[t], ah, bh); MFMA(acc2[t], ah, bl); MFMA(acc2[t], al, bh);
            }
        }
        __syncthreads();
        #pragma unroll
        for (int rr = 0; rr < 4; ++rr) {            // stage Z f32 -> OSf(B)
            const int l = 16 * w + 4 * hi4 + rr;
            #pragma unroll
            for (int t = 0; t < 4; ++t) OSf[l * 68 + 16 * t + lo4] = acc2[t][rr];
        }
        __syncthreads();
        #pragma unroll
        for (int q = 0; q < 4; ++q) {               // 256-B chunk per 16-lane group
            const int l = (tid >> 4) + 16 * q;
            const int v4 = (tid & 15) * 4;
            float4 vv = *(const float4*)(OSf + l * 68 + v4);
            *(float4*)(Zout + (size_t)h * HEADQ + (size_t)l * 4096 + (size_t)j * 64 + v4) = vv;
        }
    }
}

} // namespace

extern "C" void kernel_launch(void* const* d_in, const int* in_sizes, int n_in,
                              void* d_out, int out_size, void* d_ws, size_t ws_size,
                              hipStream_t stream) {
    const float* Q = (const float*)d_in[0];
    const float* K = (const float*)d_in[1];
    const float* V = (const float*)d_in[2];
    float* out = (float*)d_out;

    char* ws = (char*)d_ws;
    const size_t MB = 1024 * 1024;
    uint*  G   = (uint*)(ws);                   // 64 MiB packed (fallback: z staging)
    uint*  Hm  = (uint*)(ws + 64 * MB);         // 64 MiB packed
    uint*  M   = (uint*)(ws + 128 * MB);        //  1 MiB packed
    float* al  = (float*)(ws + 129 * MB);       //  1 MiB
    float* tau = (float*)(ws + 130 * MB);       //  1 MiB

    const bool bigws = ws_size >= (size_t)196 * MB;
    uint*  Ybuf = bigws ? (uint*)(ws + 131 * MB) : (uint*)out;
    float* Zdst = bigws ? out : (float*)G;

    dim3 blk(256), grid(HEADS * 64);

    kmean_kernel<<<dim3(HEADS * 64), dim3(64), 0, stream>>>(Q, M);
    bc_kernel<1, 0><<<grid, blk, 0, stream>>>(M, K, nullptr, nullptr, Hm, al, nullptr);
    da_kernel<0>   <<<grid, blk, 0, stream>>>(Q, Hm, al, nullptr, G, tau, nullptr);
    bc_kernel<0, 0><<<grid, blk, 0, stream>>>(G, K, nullptr, tau, Hm, al, nullptr);
    da_kernel<0>   <<<grid, blk, 0, stream>>>(Q, Hm, al, nullptr, G, tau, nullptr);
    bc_kernel<0, 1><<<grid, blk, 0, stream>>>(G, K, V, tau, Hm, al, Ybuf);
    da_kernel<1>   <<<grid, blk, 0, stream>>>(Q, Hm, al, Ybuf, nullptr, nullptr, Zdst);
    if (!bigws)
        hipMemcpyAsync(d_out, G, MATF * sizeof(float), hipMemcpyDeviceToDevice, stream);
}